// Round 2
// baseline (4256.436 us; speedup 1.0000x reference)
//
#include <hip/hip_runtime.h>

// Guesser fused kernel — MI355X (gfx950)
// B=4096, T=32, K=16, D=512, H=1024 (=2D), 2H=2048
// Round 1 resubmit (round 0/1 benches died on infra): fp32 VALU baseline,
// fused (no h/h2 materialization), shared-row algebra:
// concat([bcast, per-row]) @ W  ->  u[h] (once per b) + v[row][h].
// d_ws layout: x_hat (B*512 f32 = 8 MB).

#define B_  4096
#define T_  32
#define K_  16
#define D_  512
#define H_  1024
#define H2_ 2048

// ---------------------------------------------------------------------------
// Kernel 1: per-b additive attention. Computes g_hat, e[b,t], softmax, x_hat.
// One block of 256 threads per b. Thread owns 4 consecutive h (h0=4*tid).
// ---------------------------------------------------------------------------
__global__ __launch_bounds__(256, 2)
void attn_kernel(const float* __restrict__ X,    // (B,T,D)
                 const float* __restrict__ G,    // (B,K,D)
                 const float* __restrict__ W1,   // (2D,H) row-major
                 const float* __restrict__ b1,   // (H)
                 const float* __restrict__ w2,   // (H)
                 const float* __restrict__ b2,   // (1)
                 float* __restrict__ xhat)       // (B,D) out (ws)
{
    __shared__ float g_lds[D_];       // g_hat[b]
    __shared__ float Xt[D_][36];      // X[b] transposed: Xt[d][t], pad 32->36
    __shared__ float part[4][T_];     // per-wave partial e
    __shared__ float alpha_lds[T_];

    const int b   = blockIdx.x;
    const int tid = threadIdx.x;
    const int lane = tid & 63, wid = tid >> 6;
    const float* Xb = X + (size_t)b * T_ * D_;
    const float* Gb = G + (size_t)b * K_ * D_;

    // g_hat = mean_k G[b,k,:]
    for (int d = tid; d < D_; d += 256) {
        float s = 0.f;
        #pragma unroll
        for (int k = 0; k < K_; ++k) s += Gb[k * D_ + d];
        g_lds[d] = s * (1.f / K_);
    }

    // Stage X[b] transposed. f over 4096 float4 slots: t = f&31, dg = f>>5.
    // LDS write banks: (4*(4dg+j)+t)%32 -> 2 lanes/bank (free).
    #pragma unroll
    for (int it = 0; it < 16; ++it) {
        int f = it * 256 + tid;
        int t = f & 31;
        int dg = f >> 5;                       // 0..127
        const float4 xv = *reinterpret_cast<const float4*>(Xb + t * D_ + 4 * dg);
        Xt[4*dg+0][t] = xv.x;
        Xt[4*dg+1][t] = xv.y;
        Xt[4*dg+2][t] = xv.z;
        Xt[4*dg+3][t] = xv.w;
    }
    __syncthreads();

    // Main loop: u[h] = sum_i g[i]*W1[i,h];  v[t][h] = sum_i X[t,i]*W1[512+i,h]
    float u[4] = {0.f, 0.f, 0.f, 0.f};
    float v[T_][4];
    #pragma unroll
    for (int t = 0; t < T_; ++t) {
        v[t][0] = 0.f; v[t][1] = 0.f; v[t][2] = 0.f; v[t][3] = 0.f;
    }

    const int h0 = 4 * tid;
    const float* w1a = W1 + h0;                       // rows 0..511   (g part)
    const float* w1b = W1 + (size_t)D_ * H_ + h0;     // rows 512..1023 (X part)

    for (int i = 0; i < D_; ++i) {
        const float4 wa = *reinterpret_cast<const float4*>(w1a); w1a += H_;
        const float4 wb = *reinterpret_cast<const float4*>(w1b); w1b += H_;
        const float gv = g_lds[i];
        u[0] = fmaf(gv, wa.x, u[0]);
        u[1] = fmaf(gv, wa.y, u[1]);
        u[2] = fmaf(gv, wa.z, u[2]);
        u[3] = fmaf(gv, wa.w, u[3]);
        #pragma unroll
        for (int tt = 0; tt < 8; ++tt) {
            const float4 xv = *reinterpret_cast<const float4*>(&Xt[i][4 * tt]);
            v[4*tt+0][0] = fmaf(xv.x, wb.x, v[4*tt+0][0]);
            v[4*tt+0][1] = fmaf(xv.x, wb.y, v[4*tt+0][1]);
            v[4*tt+0][2] = fmaf(xv.x, wb.z, v[4*tt+0][2]);
            v[4*tt+0][3] = fmaf(xv.x, wb.w, v[4*tt+0][3]);
            v[4*tt+1][0] = fmaf(xv.y, wb.x, v[4*tt+1][0]);
            v[4*tt+1][1] = fmaf(xv.y, wb.y, v[4*tt+1][1]);
            v[4*tt+1][2] = fmaf(xv.y, wb.z, v[4*tt+1][2]);
            v[4*tt+1][3] = fmaf(xv.y, wb.w, v[4*tt+1][3]);
            v[4*tt+2][0] = fmaf(xv.z, wb.x, v[4*tt+2][0]);
            v[4*tt+2][1] = fmaf(xv.z, wb.y, v[4*tt+2][1]);
            v[4*tt+2][2] = fmaf(xv.z, wb.z, v[4*tt+2][2]);
            v[4*tt+2][3] = fmaf(xv.z, wb.w, v[4*tt+2][3]);
            v[4*tt+3][0] = fmaf(xv.w, wb.x, v[4*tt+3][0]);
            v[4*tt+3][1] = fmaf(xv.w, wb.y, v[4*tt+3][1]);
            v[4*tt+3][2] = fmaf(xv.w, wb.z, v[4*tt+3][2]);
            v[4*tt+3][3] = fmaf(xv.w, wb.w, v[4*tt+3][3]);
        }
    }

    // e[b,t] = sum_h relu(u+v+b1)*w2  (+b2), reduced across the 256 threads
    const float4 b1v = *reinterpret_cast<const float4*>(b1 + h0);
    const float4 w2v = *reinterpret_cast<const float4*>(w2 + h0);
    #pragma unroll
    for (int t = 0; t < T_; ++t) {
        float p;
        p  = fmaxf(u[0] + v[t][0] + b1v.x, 0.f) * w2v.x;
        p += fmaxf(u[1] + v[t][1] + b1v.y, 0.f) * w2v.y;
        p += fmaxf(u[2] + v[t][2] + b1v.z, 0.f) * w2v.z;
        p += fmaxf(u[3] + v[t][3] + b1v.w, 0.f) * w2v.w;
        #pragma unroll
        for (int off = 32; off >= 1; off >>= 1) p += __shfl_xor(p, off);
        if (lane == 0) part[wid][t] = p;
    }
    __syncthreads();

    // softmax over T=32 (lanes 0..31 of wave 0)
    if (tid < 32) {
        const int t = tid;
        float e = part[0][t] + part[1][t] + part[2][t] + part[3][t] + b2[0];
        float m = e;
        #pragma unroll
        for (int off = 16; off >= 1; off >>= 1) m = fmaxf(m, __shfl_xor(m, off));
        float a = expf(e - m);
        float s = a;
        #pragma unroll
        for (int off = 16; off >= 1; off >>= 1) s += __shfl_xor(s, off);
        alpha_lds[t] = a / s;
    }
    __syncthreads();

    // x_hat[b,d] = sum_t alpha[t] * X[b,t,d]  (Xt already in LDS)
    for (int d = tid; d < D_; d += 256) {
        float s = 0.f;
        #pragma unroll
        for (int tt = 0; tt < 8; ++tt) {
            const float4 xv = *reinterpret_cast<const float4*>(&Xt[d][4 * tt]);
            s = fmaf(alpha_lds[4*tt+0], xv.x, s);
            s = fmaf(alpha_lds[4*tt+1], xv.y, s);
            s = fmaf(alpha_lds[4*tt+2], xv.z, s);
            s = fmaf(alpha_lds[4*tt+3], xv.w, s);
        }
        xhat[(size_t)b * D_ + d] = s;
    }
}

// ---------------------------------------------------------------------------
// Kernel 2: guesser MLP. One block per b; thread owns 8 consecutive j (j0=8*tid).
// logits[b,k] = sum_j relu(s[j] + r[k][j] + c1[j]) * m2[j] + c2
// ---------------------------------------------------------------------------
__global__ __launch_bounds__(256, 2)
void guess_kernel(const float* __restrict__ G,     // (B,K,D)
                  const float* __restrict__ M1,    // (2D,2H)
                  const float* __restrict__ c1,    // (2H)
                  const float* __restrict__ m2,    // (2H)
                  const float* __restrict__ c2,    // (1)
                  const float* __restrict__ xhat,  // (B,D)
                  float* __restrict__ out)         // (B,K)
{
    __shared__ float xh_lds[D_];
    __shared__ float Gt[D_][20];     // G[b] transposed: Gt[d][k], pad 16->20
    __shared__ float part[4][K_];

    const int b   = blockIdx.x;
    const int tid = threadIdx.x;
    const int lane = tid & 63, wid = tid >> 6;
    const float* Gb = G + (size_t)b * K_ * D_;

    for (int d = tid; d < D_; d += 256) xh_lds[d] = xhat[(size_t)b * D_ + d];

    // Stage G[b] transposed. f over 2048 float4 slots: k = f&15, dg = f>>4.
    #pragma unroll
    for (int it = 0; it < 8; ++it) {
        int f = it * 256 + tid;
        int k = f & 15;
        int dg = f >> 4;                      // 0..127
        const float4 gv = *reinterpret_cast<const float4*>(Gb + k * D_ + 4 * dg);
        Gt[4*dg+0][k] = gv.x;
        Gt[4*dg+1][k] = gv.y;
        Gt[4*dg+2][k] = gv.z;
        Gt[4*dg+3][k] = gv.w;
    }
    __syncthreads();

    float s[8];
    #pragma unroll
    for (int j = 0; j < 8; ++j) s[j] = 0.f;
    float r[K_][8];
    #pragma unroll
    for (int k = 0; k < K_; ++k) {
        #pragma unroll
        for (int j = 0; j < 8; ++j) r[k][j] = 0.f;
    }

    const int j0 = 8 * tid;
    const float* m1a = M1 + j0;                        // rows 0..511   (xhat)
    const float* m1b = M1 + (size_t)D_ * H2_ + j0;     // rows 512..1023 (G)

    for (int i = 0; i < D_; ++i) {
        const float4 a0 = *reinterpret_cast<const float4*>(m1a);
        const float4 a1 = *reinterpret_cast<const float4*>(m1a + 4); m1a += H2_;
        const float4 q0 = *reinterpret_cast<const float4*>(m1b);
        const float4 q1 = *reinterpret_cast<const float4*>(m1b + 4); m1b += H2_;
        const float xv = xh_lds[i];
        s[0] = fmaf(xv, a0.x, s[0]);
        s[1] = fmaf(xv, a0.y, s[1]);
        s[2] = fmaf(xv, a0.z, s[2]);
        s[3] = fmaf(xv, a0.w, s[3]);
        s[4] = fmaf(xv, a1.x, s[4]);
        s[5] = fmaf(xv, a1.y, s[5]);
        s[6] = fmaf(xv, a1.z, s[6]);
        s[7] = fmaf(xv, a1.w, s[7]);
        #pragma unroll
        for (int kk = 0; kk < 4; ++kk) {
            const float4 gq = *reinterpret_cast<const float4*>(&Gt[i][4 * kk]);
            #define RROW(slot, gval)                                  \
                r[4*kk+slot][0] = fmaf(gval, q0.x, r[4*kk+slot][0]); \
                r[4*kk+slot][1] = fmaf(gval, q0.y, r[4*kk+slot][1]); \
                r[4*kk+slot][2] = fmaf(gval, q0.z, r[4*kk+slot][2]); \
                r[4*kk+slot][3] = fmaf(gval, q0.w, r[4*kk+slot][3]); \
                r[4*kk+slot][4] = fmaf(gval, q1.x, r[4*kk+slot][4]); \
                r[4*kk+slot][5] = fmaf(gval, q1.y, r[4*kk+slot][5]); \
                r[4*kk+slot][6] = fmaf(gval, q1.z, r[4*kk+slot][6]); \
                r[4*kk+slot][7] = fmaf(gval, q1.w, r[4*kk+slot][7]);
            RROW(0, gq.x)
            RROW(1, gq.y)
            RROW(2, gq.z)
            RROW(3, gq.w)
            #undef RROW
        }
    }

    const float4 c1a = *reinterpret_cast<const float4*>(c1 + j0);
    const float4 c1b = *reinterpret_cast<const float4*>(c1 + j0 + 4);
    const float4 m2a = *reinterpret_cast<const float4*>(m2 + j0);
    const float4 m2b = *reinterpret_cast<const float4*>(m2 + j0 + 4);
    #pragma unroll
    for (int k = 0; k < K_; ++k) {
        float p;
        p  = fmaxf(s[0] + r[k][0] + c1a.x, 0.f) * m2a.x;
        p += fmaxf(s[1] + r[k][1] + c1a.y, 0.f) * m2a.y;
        p += fmaxf(s[2] + r[k][2] + c1a.z, 0.f) * m2a.z;
        p += fmaxf(s[3] + r[k][3] + c1a.w, 0.f) * m2a.w;
        p += fmaxf(s[4] + r[k][4] + c1b.x, 0.f) * m2b.x;
        p += fmaxf(s[5] + r[k][5] + c1b.y, 0.f) * m2b.y;
        p += fmaxf(s[6] + r[k][6] + c1b.z, 0.f) * m2b.z;
        p += fmaxf(s[7] + r[k][7] + c1b.w, 0.f) * m2b.w;
        #pragma unroll
        for (int off = 32; off >= 1; off >>= 1) p += __shfl_xor(p, off);
        if (lane == 0) part[wid][k] = p;
    }
    __syncthreads();

    if (tid < K_) {
        out[(size_t)b * K_ + tid] =
            part[0][tid] + part[1][tid] + part[2][tid] + part[3][tid] + c2[0];
    }
}

extern "C" void kernel_launch(void* const* d_in, const int* in_sizes, int n_in,
                              void* d_out, int out_size, void* d_ws, size_t ws_size,
                              hipStream_t stream) {
    const float* X  = (const float*)d_in[0];
    const float* G  = (const float*)d_in[1];
    const float* W1 = (const float*)d_in[2];
    const float* b1 = (const float*)d_in[3];
    const float* w2 = (const float*)d_in[4];
    const float* b2 = (const float*)d_in[5];
    const float* M1 = (const float*)d_in[6];
    const float* c1 = (const float*)d_in[7];
    const float* m2 = (const float*)d_in[8];
    const float* c2 = (const float*)d_in[9];
    float* out  = (float*)d_out;
    float* xhat = (float*)d_ws;   // B*D f32 = 8 MB

    const int B = in_sizes[0] / (T_ * D_);   // 4096

    attn_kernel<<<B, 256, 0, stream>>>(X, G, W1, b1, w2, b2, xhat);
    guess_kernel<<<B, 256, 0, stream>>>(G, M1, c1, m2, c2, xhat, out);
}

// Round 3
// 1596.756 us; speedup vs baseline: 2.6657x; 2.6657x over previous
//
#include <hip/hip_runtime.h>

// Guesser fused — MI355X gfx950 — Round 3: bf16 MFMA path.
// B=4096, T=32, K=16, D=512, H=1024, 2H=2048.
// Pipeline: pack W1/M1 -> U=ghat@W1top -> attn(v=X@W1bot fused) -> S=xhat@M1top
//           -> guess(r=G@M1bot fused).
// All GEMM B-operands pre-packed in MFMA fragment order (16B/lane loads).
// A-operands staged in LDS bf16 with XOR swizzle byte^=((row&7)<<4).
// ws (34 MB): W1tp 1M | W1bp 1M | M1tp 2M | M1bp 2M | U 8M | xhat 4M | S 16M.

#define T_  32
#define K_  16
#define D_  512
#define H_  1024
#define H2_ 2048

typedef float  f32x4  __attribute__((ext_vector_type(4)));
typedef __bf16 bf16x8 __attribute__((ext_vector_type(8)));
typedef unsigned short u16x8 __attribute__((ext_vector_type(8)));
typedef unsigned short u16x4 __attribute__((ext_vector_type(4)));

union BF8 { u16x8 u; bf16x8 b; };

__device__ __forceinline__ unsigned short f2b(float x) {
    union { __bf16 b; unsigned short u; } c; c.b = (__bf16)x; return c.u;
}
__device__ __forceinline__ float b2f(unsigned short x) {
    union { unsigned short u; __bf16 b; } c; c.u = x; return (float)c.b;
}
__device__ __forceinline__ bf16x8 lds_frag(const char* p) {
    BF8 c; c.u = *(const u16x8*)p; return c.b;
}
__device__ __forceinline__ bf16x8 glb_frag(const unsigned short* p) {
    BF8 c; c.u = *(const u16x8*)p; return c.b;
}
#define MFMA16(a, b, c) __builtin_amdgcn_mfma_f32_16x16x32_bf16(a, b, c, 0, 0, 0)

// ---------------------------------------------------------------------------
// pack: W[row0+k][c] (fp32, ld cols) -> dst fragments
// dst[((nt*16+ks)*64 + lane)*8 + j] = bf16( W[row0 + 32*ks + 8*(lane>>4) + j][16*nt + (lane&15)] )
// ---------------------------------------------------------------------------
__global__ void pack_kernel(const float* __restrict__ src,
                            unsigned short* __restrict__ dst,
                            int ld, int row0, int ntiles) {
    int tid = blockIdx.x * 256 + threadIdx.x;
    if (tid >= ntiles * 16 * 64) return;
    int lane = tid & 63;
    int idx  = tid >> 6;               // nt*16 + ks
    int nt = idx >> 4, ks = idx & 15;
    int k = 32 * ks + 8 * (lane >> 4);
    int c = 16 * nt + (lane & 15);
    const float* s = src + (size_t)(row0 + k) * ld + c;
    unsigned short* d = dst + ((size_t)idx * 64 + lane) * 8;
    #pragma unroll
    for (int j = 0; j < 8; ++j) d[j] = f2b(s[(size_t)j * ld]);
}

// ---------------------------------------------------------------------------
// gemm: C(bf16, Mx NCOLS) = A(32 rows x 512) @ Bp(packed 512 x NCOLS)
// MODE 0: A row r = mean_k G[(mb*32+r)][k][:]   (fp32 source)
// MODE 1: A row r = Abf[(mb*32+r)][:]           (bf16 source)
// ---------------------------------------------------------------------------
template<int NCOLS, int MODE>
__global__ __launch_bounds__(256, 2)
void gemm_kernel(const float* __restrict__ Gsrc,
                 const unsigned short* __restrict__ Abf,
                 const unsigned short* __restrict__ Bp,
                 unsigned short* __restrict__ Cbf) {
    __shared__ char Al[32 * 1024];
    const int tid = threadIdx.x, lane = tid & 63, wid = tid >> 6;
    const int mb = blockIdx.x;

    if (MODE == 0) {
        const int d0 = tid * 2;                         // 2 cols per thread
        for (int r = 0; r < 32; ++r) {
            float sx = 0.f, sy = 0.f;
            #pragma unroll
            for (int k = 0; k < 16; ++k) {
                const float2 g = *(const float2*)(Gsrc +
                    ((size_t)(mb * 32 + r) * 16 + k) * D_ + d0);
                sx += g.x; sy += g.y;
            }
            sx *= (1.f / 16.f); sy *= (1.f / 16.f);
            unsigned int pk = (unsigned int)f2b(sx) | ((unsigned int)f2b(sy) << 16);
            *(unsigned int*)(Al + r * 1024 + ((4 * tid) ^ (16 * (r & 7)))) = pk;
        }
    } else {
        #pragma unroll
        for (int it = 0; it < 8; ++it) {
            int q = it * 256 + tid;                     // 16B chunk id
            int r = q >> 6, cb = (q & 63) * 16;         // 64 chunks per row
            u16x8 v = *(const u16x8*)(Abf + (size_t)(mb * 32 + r) * 512 + cb / 2);
            *(u16x8*)(Al + r * 1024 + (cb ^ (16 * (r & 7)))) = v;
        }
    }
    __syncthreads();

    constexpr int NTW = NCOLS / 64;       // n-tiles per wave (16 or 32)
    constexpr int CHUNKS = NTW / 4;
    const int wq = wid * (NCOLS / 4);

    for (int ch = 0; ch < CHUNKS; ++ch) {
        f32x4 acc[2][4];
        #pragma unroll
        for (int m = 0; m < 2; ++m)
            #pragma unroll
            for (int n = 0; n < 4; ++n) acc[m][n] = (f32x4){0.f, 0.f, 0.f, 0.f};

        for (int ks = 0; ks < 16; ++ks) {
            const int koff = (ks * 64 + 16 * (lane >> 4)) ^ (16 * (lane & 7));
            bf16x8 a0 = lds_frag(Al + ((lane & 15)) * 1024 + koff);
            bf16x8 a1 = lds_frag(Al + (16 + (lane & 15)) * 1024 + koff);
            #pragma unroll
            for (int nt = 0; nt < 4; ++nt) {
                int ntg = wq / 16 + ch * 4 + nt;
                bf16x8 b = glb_frag(Bp + ((size_t)(ntg * 16 + ks) * 64 + lane) * 8);
                acc[0][nt] = MFMA16(a0, b, acc[0][nt]);
                acc[1][nt] = MFMA16(a1, b, acc[1][nt]);
            }
        }
        #pragma unroll
        for (int nt = 0; nt < 4; ++nt) {
            int col = wq + ch * 64 + nt * 16 + (lane & 15);
            #pragma unroll
            for (int m = 0; m < 2; ++m)
                #pragma unroll
                for (int j = 0; j < 4; ++j) {
                    int row = mb * 32 + m * 16 + (lane >> 4) * 4 + j;
                    Cbf[(size_t)row * NCOLS + col] = f2b(acc[m][nt][j]);
                }
        }
    }
}

// ---------------------------------------------------------------------------
// attn: 2 batches per block. v = X[b](32x512) @ W1bot -> e -> softmax -> xhat.
// ---------------------------------------------------------------------------
__global__ __launch_bounds__(256, 2)
void attn_kernel(const float* __restrict__ X,
                 const unsigned short* __restrict__ W1bp,
                 const float* __restrict__ b1,
                 const float* __restrict__ w2,
                 const float* __restrict__ b2,
                 const unsigned short* __restrict__ Ubf,
                 unsigned short* __restrict__ xhat_bf) {
    __shared__ char Xl[64 * 1024];           // rows: b0 t0..31, b1 t0..31
    __shared__ float part[4][64];
    __shared__ float alpha_l[64];

    const int tid = threadIdx.x, lane = tid & 63, wid = tid >> 6;
    const int b0 = blockIdx.x * 2;
    const float* Xbase = X + (size_t)b0 * T_ * D_;

    // stage X (2 batches) fp32 -> bf16 LDS, swizzled
    #pragma unroll 4
    for (int it = 0; it < 32; ++it) {
        int q = it * 256 + tid;              // float4 id
        int r = q >> 7, qc = q & 127;        // 128 quads per row
        float4 xv = *(const float4*)(Xbase + (size_t)r * D_ + qc * 4);
        u16x4 v; v[0] = f2b(xv.x); v[1] = f2b(xv.y); v[2] = f2b(xv.z); v[3] = f2b(xv.w);
        *(u16x4*)(Xl + r * 1024 + ((qc * 8) ^ (16 * (r & 7)))) = v;
    }
    __syncthreads();

    float eacc[4][4];
    #pragma unroll
    for (int m = 0; m < 4; ++m)
        #pragma unroll
        for (int j = 0; j < 4; ++j) eacc[m][j] = 0.f;

    const int wq = wid * 256;
    for (int ch = 0; ch < 4; ++ch) {
        f32x4 acc[4][4];
        #pragma unroll
        for (int m = 0; m < 4; ++m)
            #pragma unroll
            for (int n = 0; n < 4; ++n) acc[m][n] = (f32x4){0.f, 0.f, 0.f, 0.f};

        for (int ks = 0; ks < 16; ++ks) {
            const int koff = (ks * 64 + 16 * (lane >> 4)) ^ (16 * (lane & 7));
            bf16x8 a[4];
            #pragma unroll
            for (int m = 0; m < 4; ++m)
                a[m] = lds_frag(Xl + (m * 16 + (lane & 15)) * 1024 + koff);
            #pragma unroll
            for (int nt = 0; nt < 4; ++nt) {
                int ntg = wid * 16 + ch * 4 + nt;
                bf16x8 b = glb_frag(W1bp + ((size_t)(ntg * 16 + ks) * 64 + lane) * 8);
                #pragma unroll
                for (int m = 0; m < 4; ++m) acc[m][nt] = MFMA16(a[m], b, acc[m][nt]);
            }
        }
        // fused epilogue: e partials
        #pragma unroll
        for (int nt = 0; nt < 4; ++nt) {
            int h = wq + ch * 64 + nt * 16 + (lane & 15);
            float w2v = w2[h], b1v = b1[h];
            float u0 = b2f(Ubf[(size_t)b0 * H_ + h]);
            float u1 = b2f(Ubf[(size_t)(b0 + 1) * H_ + h]);
            #pragma unroll
            for (int m = 0; m < 4; ++m) {
                float ub = (m < 2) ? u0 : u1;
                #pragma unroll
                for (int j = 0; j < 4; ++j)
                    eacc[m][j] += fmaxf(acc[m][nt][j] + ub + b1v, 0.f) * w2v;
            }
        }
    }

    #pragma unroll
    for (int m = 0; m < 4; ++m)
        #pragma unroll
        for (int j = 0; j < 4; ++j) {
            float v = eacc[m][j];
            v += __shfl_xor(v, 1); v += __shfl_xor(v, 2);
            v += __shfl_xor(v, 4); v += __shfl_xor(v, 8);
            if ((lane & 15) == 0) part[wid][m * 16 + (lane >> 4) * 4 + j] = v;
        }
    __syncthreads();

    if (tid < 64) {
        float e = part[0][tid] + part[1][tid] + part[2][tid] + part[3][tid] + b2[0];
        float mx = e;
        mx = fmaxf(mx, __shfl_xor(mx, 1));  mx = fmaxf(mx, __shfl_xor(mx, 2));
        mx = fmaxf(mx, __shfl_xor(mx, 4));  mx = fmaxf(mx, __shfl_xor(mx, 8));
        mx = fmaxf(mx, __shfl_xor(mx, 16));
        float a = expf(e - mx);
        float s = a;
        s += __shfl_xor(s, 1); s += __shfl_xor(s, 2); s += __shfl_xor(s, 4);
        s += __shfl_xor(s, 8); s += __shfl_xor(s, 16);
        alpha_l[tid] = a / s;
    }
    __syncthreads();

    // xhat[b][d] = sum_t alpha * X  (from bf16 LDS), store bf16
    const int bi = tid >> 7, c4 = tid & 127;
    float s4[4] = {0.f, 0.f, 0.f, 0.f};
    #pragma unroll 4
    for (int tt = 0; tt < 32; ++tt) {
        int r = bi * 32 + tt;
        u16x4 xv = *(const u16x4*)(Xl + r * 1024 + ((c4 * 8) ^ (16 * (tt & 7))));
        float al = alpha_l[r];
        s4[0] += al * b2f(xv[0]); s4[1] += al * b2f(xv[1]);
        s4[2] += al * b2f(xv[2]); s4[3] += al * b2f(xv[3]);
    }
    u16x4 o; o[0] = f2b(s4[0]); o[1] = f2b(s4[1]); o[2] = f2b(s4[2]); o[3] = f2b(s4[3]);
    *(u16x4*)(xhat_bf + (size_t)(b0 + bi) * D_ + c4 * 4) = o;
}

// ---------------------------------------------------------------------------
// guess: 4 batches per block. r = G[b](16x512) @ M1bot -> logits.
// ---------------------------------------------------------------------------
__global__ __launch_bounds__(256, 2)
void guess_kernel(const float* __restrict__ G,
                  const unsigned short* __restrict__ M1bp,
                  const float* __restrict__ c1,
                  const float* __restrict__ m2,
                  const float* __restrict__ c2,
                  const unsigned short* __restrict__ Sbf,
                  float* __restrict__ out) {
    __shared__ char Gl[64 * 1024];           // rows: bi*16 + k
    __shared__ float part[4][64];

    const int tid = threadIdx.x, lane = tid & 63, wid = tid >> 6;
    const int b0 = blockIdx.x * 4;
    const float* Gbase = G + (size_t)b0 * K_ * D_;

    #pragma unroll 4
    for (int it = 0; it < 32; ++it) {
        int q = it * 256 + tid;
        int r = q >> 7, qc = q & 127;
        float4 gv = *(const float4*)(Gbase + (size_t)r * D_ + qc * 4);
        u16x4 v; v[0] = f2b(gv.x); v[1] = f2b(gv.y); v[2] = f2b(gv.z); v[3] = f2b(gv.w);
        *(u16x4*)(Gl + r * 1024 + ((qc * 8) ^ (16 * (r & 7)))) = v;
    }
    __syncthreads();

    float lacc[4][4];
    #pragma unroll
    for (int m = 0; m < 4; ++m)
        #pragma unroll
        for (int j = 0; j < 4; ++j) lacc[m][j] = 0.f;

    const int wq = wid * 512;
    for (int ch = 0; ch < 8; ++ch) {
        f32x4 acc[4][4];
        #pragma unroll
        for (int m = 0; m < 4; ++m)
            #pragma unroll
            for (int n = 0; n < 4; ++n) acc[m][n] = (f32x4){0.f, 0.f, 0.f, 0.f};

        for (int ks = 0; ks < 16; ++ks) {
            const int koff = (ks * 64 + 16 * (lane >> 4)) ^ (16 * (lane & 7));
            bf16x8 a[4];
            #pragma unroll
            for (int m = 0; m < 4; ++m)
                a[m] = lds_frag(Gl + (m * 16 + (lane & 15)) * 1024 + koff);
            #pragma unroll
            for (int nt = 0; nt < 4; ++nt) {
                int ntg = wid * 32 + ch * 4 + nt;
                bf16x8 b = glb_frag(M1bp + ((size_t)(ntg * 16 + ks) * 64 + lane) * 8);
                #pragma unroll
                for (int m = 0; m < 4; ++m) acc[m][nt] = MFMA16(a[m], b, acc[m][nt]);
            }
        }
        #pragma unroll
        for (int nt = 0; nt < 4; ++nt) {
            int jc = wq + ch * 64 + nt * 16 + (lane & 15);
            float c1v = c1[jc], m2v = m2[jc];
            float sv[4];
            #pragma unroll
            for (int m = 0; m < 4; ++m)
                sv[m] = b2f(Sbf[(size_t)(b0 + m) * H2_ + jc]);
            #pragma unroll
            for (int m = 0; m < 4; ++m)
                #pragma unroll
                for (int j = 0; j < 4; ++j)
                    lacc[m][j] += fmaxf(acc[m][nt][j] + sv[m] + c1v, 0.f) * m2v;
        }
    }

    #pragma unroll
    for (int m = 0; m < 4; ++m)
        #pragma unroll
        for (int j = 0; j < 4; ++j) {
            float v = lacc[m][j];
            v += __shfl_xor(v, 1); v += __shfl_xor(v, 2);
            v += __shfl_xor(v, 4); v += __shfl_xor(v, 8);
            if ((lane & 15) == 0) part[wid][m * 16 + (lane >> 4) * 4 + j] = v;
        }
    __syncthreads();

    if (tid < 64) {
        float v = part[0][tid] + part[1][tid] + part[2][tid] + part[3][tid] + c2[0];
        out[(size_t)(b0 + (tid >> 4)) * K_ + (tid & 15)] = v;
    }
}

// ---------------------------------------------------------------------------
extern "C" void kernel_launch(void* const* d_in, const int* in_sizes, int n_in,
                              void* d_out, int out_size, void* d_ws, size_t ws_size,
                              hipStream_t stream) {
    const float* X  = (const float*)d_in[0];
    const float* G  = (const float*)d_in[1];
    const float* W1 = (const float*)d_in[2];
    const float* b1 = (const float*)d_in[3];
    const float* w2 = (const float*)d_in[4];
    const float* b2 = (const float*)d_in[5];
    const float* M1 = (const float*)d_in[6];
    const float* c1 = (const float*)d_in[7];
    const float* m2 = (const float*)d_in[8];
    const float* c2 = (const float*)d_in[9];
    float* out = (float*)d_out;

    char* ws = (char*)d_ws;
    unsigned short* W1tp = (unsigned short*)(ws);                       // 1 MB
    unsigned short* W1bp = (unsigned short*)(ws + (1u << 20));          // 1 MB
    unsigned short* M1tp = (unsigned short*)(ws + (2u << 20));          // 2 MB
    unsigned short* M1bp = (unsigned short*)(ws + (4u << 20));          // 2 MB
    unsigned short* Ubf  = (unsigned short*)(ws + (6u << 20));          // 8 MB
    unsigned short* xhbf = (unsigned short*)(ws + (14u << 20));         // 4 MB
    unsigned short* Sbf  = (unsigned short*)(ws + (18u << 20));         // 16 MB

    const int B = in_sizes[0] / (T_ * D_);   // 4096

    // pack weights into MFMA B-fragment order
    pack_kernel<<<(64 * 1024) / 256, 256, 0, stream>>>(W1, W1tp, H_, 0, 64);
    pack_kernel<<<(64 * 1024) / 256, 256, 0, stream>>>(W1, W1bp, H_, D_, 64);
    pack_kernel<<<(128 * 1024) / 256, 256, 0, stream>>>(M1, M1tp, H2_, 0, 128);
    pack_kernel<<<(128 * 1024) / 256, 256, 0, stream>>>(M1, M1bp, H2_, D_, 128);

    // U = ghat @ W1top   (ghat from G on the fly)
    gemm_kernel<H_, 0><<<B / 32, 256, 0, stream>>>(G, nullptr, W1tp, Ubf);
    // attention + xhat
    attn_kernel<<<B / 2, 256, 0, stream>>>(X, W1bp, b1, w2, b2, Ubf, xhbf);
    // S = xhat @ M1top
    gemm_kernel<H2_, 1><<<B / 32, 256, 0, stream>>>(nullptr, xhbf, M1tp, Sbf);
    // guesser logits
    guess_kernel<<<B / 4, 256, 0, stream>>>(G, M1bp, c1, m2, c2, Sbf, out);
}